// Round 1
// baseline (1780.070 us; speedup 1.0000x reference)
//
#include <hip/hip_runtime.h>
#include <math.h>

// infoFSM mask-scorer MLP, fully fused fp32 kernel for gfx950.
// ref: x=gelu(in@W_L^T); x=gelu(x@W_l1^T); x=gelu(x@W_l2^T); p=sigmoid(x@w3);
//      cm=(p*prev_m>0.5)?1:0 (+1e-10); mask=(int)cm; out=in*cm
// No MFMA: threshold-at-0.5 needs fp32 fidelity (bf16 flips mask bits), and
// CDNA4 has no fp32-input MFMA anyway -> fp32 VALU GEMM, floor ~357us.

namespace {

constexpr int R_ROWS = 128 * 512;   // B*N = 65536
constexpr int D0 = 512, D1 = 512, D2 = 256, D3 = 128;
constexpr int TM = 32;              // rows per block
constexpr int NT = 256;             // threads per block
constexpr int BK = 16;              // K-chunk
constexpr int PB = 20;              // LDS pitch for weight/A tiles (floats, 80B: 16B-aligned,
                                    // bank starts 4-aligned & uniform -> conflict-free b128)
constexpr int PX3 = 132;            // X3 pitch (spreads banks for the 128-dot phase)

// LDS float offsets (union layout, 34816 floats = 139,264 B <= 160 KB/WG on gfx950)
constexpr int OFF_X1 = 0;                      // 32*512 = 16384 floats
constexpr int OFF_B  = OFF_X1 + TM * D1;       // 512*20 = 10240 floats
constexpr int OFF_X2 = OFF_B + D1 * PB;        // 32*256 =  8192 floats
constexpr int SMEM_FLOATS = OFF_X2 + TM * D2;  // 34816

__device__ __forceinline__ float gelu_exact(float x) {
    // torch nn.GELU default (erf form)
    return 0.5f * x * (1.0f + erff(x * 0.70710678118654752440f));
}

__global__ __launch_bounds__(NT, 1) void fused_mlp_mask(
    const float* __restrict__ input,   // [R, 512]
    const float* __restrict__ prev_m,  // [R]
    const float* __restrict__ W_L,     // [512, 512] row-major (e, d)
    const float* __restrict__ W_l1,    // [256, 512]
    const float* __restrict__ W_l2,    // [128, 256]
    const float* __restrict__ W_l3,    // [1, 128]
    float* __restrict__ out,           // [R, 512]
    float* __restrict__ mask_out,      // [R]  (int values written as float)
    float* __restrict__ currm_out)     // [R]
{
    __shared__ float smem[SMEM_FLOATS];
    float* sX1 = smem + OFF_X1;   // X1 activations (32 x 512)
    float* sB  = smem + OFF_B;    // weight tile staging (all layers), [e][PB]
    float* sX2 = smem + OFF_X2;   // X2 activations (32 x 256)
    float* sA  = sX2;             // alias: GEMM1 A staging (32 x PB), dead before X2 written
    float* sX3 = sX1;             // alias: X3 (32 x 132), X1 dead after GEMM2
    float* sM  = sX2;             // alias: per-row scale (32), X2 dead after GEMM3

    const int tid  = threadIdx.x;
    const int row0 = blockIdx.x * TM;
    const int tcol = tid & 63;    // 0..63 (col group)
    const int r0   = (tid >> 6) * 8;  // 8 rows per thread, wave-uniform -> LDS broadcast

    // ---------------- GEMM1: X1 = gelu(in @ W_L^T), 32x512, K=512 ----------------
    float acc[8][8];
    #pragma unroll
    for (int i = 0; i < 8; ++i)
        #pragma unroll
        for (int j = 0; j < 8; ++j) acc[i][j] = 0.0f;

    for (int k0 = 0; k0 < D0; k0 += BK) {
        if (tid < 128) {  // stage A: 32 rows x 16 k = 128 float4
            int r = tid >> 2, g = (tid & 3) << 2;
            *(float4*)&sA[r * PB + g] = *(const float4*)&input[(row0 + r) * D0 + k0 + g];
        }
        #pragma unroll
        for (int it = 0; it < 8; ++it) {  // stage B: 512 e x 16 k = 2048 float4
            int j = tid + NT * it;
            int e = j >> 2, g = (j & 3) << 2;
            *(float4*)&sB[e * PB + g] = *(const float4*)&W_L[e * D0 + k0 + g];
        }
        __syncthreads();
        #pragma unroll
        for (int kk = 0; kk < BK; kk += 4) {
            float4 a[8], b[8];
            #pragma unroll
            for (int i = 0; i < 8; ++i) a[i] = *(float4*)&sA[(r0 + i) * PB + kk];
            #pragma unroll
            for (int j = 0; j < 8; ++j) b[j] = *(float4*)&sB[(tcol + 64 * j) * PB + kk];
            #pragma unroll
            for (int i = 0; i < 8; ++i)
                #pragma unroll
                for (int j = 0; j < 8; ++j) {
                    acc[i][j] = fmaf(a[i].x, b[j].x, acc[i][j]);
                    acc[i][j] = fmaf(a[i].y, b[j].y, acc[i][j]);
                    acc[i][j] = fmaf(a[i].z, b[j].z, acc[i][j]);
                    acc[i][j] = fmaf(a[i].w, b[j].w, acc[i][j]);
                }
        }
        __syncthreads();
    }
    #pragma unroll
    for (int i = 0; i < 8; ++i)
        #pragma unroll
        for (int j = 0; j < 8; ++j)
            sX1[(r0 + i) * D1 + tcol + 64 * j] = gelu_exact(acc[i][j]);
    __syncthreads();

    // ---------------- GEMM2: X2 = gelu(X1 @ W_l1^T), 32x256, K=512 ----------------
    float acc2[8][4];
    #pragma unroll
    for (int i = 0; i < 8; ++i)
        #pragma unroll
        for (int j = 0; j < 4; ++j) acc2[i][j] = 0.0f;

    for (int k0 = 0; k0 < D1; k0 += BK) {
        #pragma unroll
        for (int it = 0; it < 4; ++it) {  // stage W_l1 tile: 256 e x 16 k
            int j = tid + NT * it;
            int e = j >> 2, g = (j & 3) << 2;
            *(float4*)&sB[e * PB + g] = *(const float4*)&W_l1[e * D1 + k0 + g];
        }
        __syncthreads();
        #pragma unroll
        for (int kk = 0; kk < BK; kk += 4) {
            float4 a[8], b[4];
            #pragma unroll
            for (int i = 0; i < 8; ++i) a[i] = *(float4*)&sX1[(r0 + i) * D1 + k0 + kk];
            #pragma unroll
            for (int j = 0; j < 4; ++j) b[j] = *(float4*)&sB[(tcol + 64 * j) * PB + kk];
            #pragma unroll
            for (int i = 0; i < 8; ++i)
                #pragma unroll
                for (int j = 0; j < 4; ++j) {
                    acc2[i][j] = fmaf(a[i].x, b[j].x, acc2[i][j]);
                    acc2[i][j] = fmaf(a[i].y, b[j].y, acc2[i][j]);
                    acc2[i][j] = fmaf(a[i].z, b[j].z, acc2[i][j]);
                    acc2[i][j] = fmaf(a[i].w, b[j].w, acc2[i][j]);
                }
        }
        __syncthreads();
    }
    #pragma unroll
    for (int i = 0; i < 8; ++i)
        #pragma unroll
        for (int j = 0; j < 4; ++j)
            sX2[(r0 + i) * D2 + tcol + 64 * j] = gelu_exact(acc2[i][j]);
    __syncthreads();

    // ---------------- GEMM3: X3 = gelu(X2 @ W_l2^T), 32x128, K=256 ----------------
    float acc3[8][2];
    #pragma unroll
    for (int i = 0; i < 8; ++i)
        #pragma unroll
        for (int j = 0; j < 2; ++j) acc3[i][j] = 0.0f;

    for (int k0 = 0; k0 < D2; k0 += BK) {
        #pragma unroll
        for (int it = 0; it < 2; ++it) {  // stage W_l2 tile: 128 e x 16 k
            int j = tid + NT * it;
            int e = j >> 2, g = (j & 3) << 2;
            *(float4*)&sB[e * PB + g] = *(const float4*)&W_l2[e * D2 + k0 + g];
        }
        __syncthreads();
        #pragma unroll
        for (int kk = 0; kk < BK; kk += 4) {
            float4 a[8], b[2];
            #pragma unroll
            for (int i = 0; i < 8; ++i) a[i] = *(float4*)&sX2[(r0 + i) * D2 + k0 + kk];
            #pragma unroll
            for (int j = 0; j < 2; ++j) b[j] = *(float4*)&sB[(tcol + 64 * j) * PB + kk];
            #pragma unroll
            for (int i = 0; i < 8; ++i)
                #pragma unroll
                for (int j = 0; j < 2; ++j) {
                    acc3[i][j] = fmaf(a[i].x, b[j].x, acc3[i][j]);
                    acc3[i][j] = fmaf(a[i].y, b[j].y, acc3[i][j]);
                    acc3[i][j] = fmaf(a[i].z, b[j].z, acc3[i][j]);
                    acc3[i][j] = fmaf(a[i].w, b[j].w, acc3[i][j]);
                }
        }
        __syncthreads();
    }
    #pragma unroll
    for (int i = 0; i < 8; ++i)
        #pragma unroll
        for (int j = 0; j < 2; ++j)
            sX3[(r0 + i) * PX3 + tcol + 64 * j] = gelu_exact(acc3[i][j]);
    __syncthreads();

    // -------- layer4: prob = sigmoid(X3 @ w3); threshold; per-row scale --------
    if (tid < TM) {
        float dot = 0.0f;
        #pragma unroll 8
        for (int k = 0; k < D3; ++k)
            dot = fmaf(sX3[tid * PX3 + k], W_l3[k], dot);
        float prob = 1.0f / (1.0f + expf(-dot));
        float cm_pre = prob * prev_m[row0 + tid];
        float st = (cm_pre > 0.5f) ? 1.0f : 0.0f;   // STE hard threshold
        float cm = st + 1e-10f;
        sM[tid] = cm;
        mask_out[row0 + tid]  = st;   // int 0/1 written as float into fp32 out buffer
        currm_out[row0 + tid] = cm;
    }
    __syncthreads();

    // ---------------- epilogue: out = input * curr_m ----------------
    #pragma unroll
    for (int it = 0; it < 16; ++it) {
        int j = tid + NT * it;        // < 4096 float4 = 32 rows x 128
        int r = j >> 7;
        int q = (j & 127) << 2;
        float m = sM[r];
        float4 v = *(const float4*)&input[(row0 + r) * D0 + q];
        float4 o;
        o.x = v.x * m; o.y = v.y * m; o.z = v.z * m; o.w = v.w * m;
        *(float4*)&out[(row0 + r) * D0 + q] = o;
    }
}

}  // namespace

extern "C" void kernel_launch(void* const* d_in, const int* in_sizes, int n_in,
                              void* d_out, int out_size, void* d_ws, size_t ws_size,
                              hipStream_t stream) {
    const float* input  = (const float*)d_in[0];
    // d_in[1] = attention_mask: unused by the reference computation
    const float* prev_m = (const float*)d_in[2];
    const float* W_L    = (const float*)d_in[3];
    const float* W_l1   = (const float*)d_in[4];
    const float* W_l2   = (const float*)d_in[5];
    const float* W_l3   = (const float*)d_in[6];

    float* out_p   = (float*)d_out;                      // [R, 512]
    float* mask_p  = out_p + (size_t)R_ROWS * D0;        // [R]
    float* currm_p = mask_p + R_ROWS;                    // [R]

    dim3 grid(R_ROWS / TM), block(NT);
    fused_mlp_mask<<<grid, block, 0, stream>>>(input, prev_m, W_L, W_l1, W_l2, W_l3,
                                               out_p, mask_p, currm_p);
}

// Round 2
// 1110.474 us; speedup vs baseline: 1.6030x; 1.6030x over previous
//
#include <hip/hip_runtime.h>
#include <math.h>

// infoFSM mask-scorer MLP, fully fused fp32 kernel for gfx950. Round 2.
// ref: x=gelu(in@W_L^T); x=gelu(x@W_l1^T); x=gelu(x@W_l2^T); p=sigmoid(x@w3);
//      cm=(p*prev_m>0.5)?1:0 (+1e-10); mask=(int)cm; out=in*cm
// fp32 VALU GEMM (no fp32 MFMA on CDNA4; threshold@0.5 needs fp32 fidelity).
// R2 changes vs R1 (1712us, VALUBusy 37%, 1.95e8 LDS conflicts, occ 12%):
//  - 512 threads (8 waves, 2/SIMD) instead of 256 (1/SIMD)
//  - k-major weight tile in LDS -> lane-contiguous b128 B-reads (conflict-free)
//  - A-fragment reads wave-uniform -> LDS broadcast (free)
//  - register-prefetch double buffering of weight tiles (hide L2 latency)

namespace {

constexpr int R_ROWS = 128 * 512;   // B*N = 65536
constexpr int D0 = 512, D1 = 512, D2 = 256, D3 = 128;
constexpr int TM = 32;              // rows per block
constexpr int NT = 512;             // threads per block (8 waves)
constexpr int BK = 16;              // K-chunk per tile
constexpr int PE = 520;             // k-major weight tile pitch (floats per k-row)
constexpr int PA = 20;              // sA pitch
constexpr int PX3 = 132;            // X3 pitch

// LDS float offsets: sA(640) + sBt(16*520=8320) + sX1(16384) + sX2(8192)
constexpr int OFF_A  = 0;
constexpr int OFF_B  = OFF_A + TM * PA;        // 640
constexpr int OFF_X1 = OFF_B + BK * PE;        // 8960
constexpr int OFF_X2 = OFF_X1 + TM * D1;       // 25344
constexpr int SMEM_FLOATS = OFF_X2 + TM * D2;  // 33536 floats = 134144 B

__device__ __forceinline__ float gelu_exact(float x) {
    return 0.5f * x * (1.0f + erff(x * 0.70710678118654752440f));
}

__global__ __launch_bounds__(NT, 2) void fused_mlp_mask(
    const float* __restrict__ input,   // [R, 512]
    const float* __restrict__ prev_m,  // [R]
    const float* __restrict__ W_L,     // [512, 512]
    const float* __restrict__ W_l1,    // [256, 512]
    const float* __restrict__ W_l2,    // [128, 256]
    const float* __restrict__ W_l3,    // [1, 128]
    float* __restrict__ out,           // [R, 512]
    float* __restrict__ mask_out,      // [R]
    float* __restrict__ currm_out)     // [R]
{
    __shared__ float smem[SMEM_FLOATS];
    float* sA  = smem + OFF_A;    // A tile [32][PA], k-contiguous per row
    float* sBt = smem + OFF_B;    // weight tile, k-major: [k][e] pitch PE
    float* sX1 = smem + OFF_X1;   // X1 [32][512]
    float* sX2 = smem + OFF_X2;   // X2 [32][256]
    float* sX3 = sX1;             // alias (X1 dead after GEMM2): [32][PX3]
    float* sM  = sX2;             // alias (X2 dead after GEMM3): [32]

    const int tid  = threadIdx.x;
    const int wid  = tid >> 6;
    const int tcol = tid & 63;
    const int row0 = blockIdx.x * TM;

    // ================= GEMM1: X1 = gelu(in @ W_L^T), 32x512, K=512 ============
    {
        const int rg = (wid & 3) * 8;               // 8 rows, wave-uniform
        const int cb = (wid >> 2) * 256 + 4 * tcol; // 4 cols, lane-contiguous
        const int e  = tid;                         // staging: one weight row each

        float acc[8][4];
        #pragma unroll
        for (int i = 0; i < 8; ++i)
            #pragma unroll
            for (int j = 0; j < 4; ++j) acc[i][j] = 0.0f;

        // prologue: stage tile 0
        {
            float4 w[4], av;
            #pragma unroll
            for (int g = 0; g < 4; ++g) w[g] = *(const float4*)&W_L[e * D0 + 4 * g];
            if (tid < 128) {
                int r = tid >> 2, g = tid & 3;
                av = *(const float4*)&input[(row0 + r) * D0 + 4 * g];
            }
            #pragma unroll
            for (int g = 0; g < 4; ++g) {
                sBt[(4 * g + 0) * PE + e] = w[g].x;
                sBt[(4 * g + 1) * PE + e] = w[g].y;
                sBt[(4 * g + 2) * PE + e] = w[g].z;
                sBt[(4 * g + 3) * PE + e] = w[g].w;
            }
            if (tid < 128) {
                int r = tid >> 2, g = tid & 3;
                *(float4*)&sA[r * PA + 4 * g] = av;
            }
        }
        __syncthreads();

        for (int t = 0; t < D0 / BK; ++t) {
            // prefetch tile t+1 into registers (latency hidden under compute)
            float4 w[4], av;
            const bool more = (t + 1) < (D0 / BK);
            if (more) {
                const int k0n = (t + 1) * BK;
                #pragma unroll
                for (int g = 0; g < 4; ++g)
                    w[g] = *(const float4*)&W_L[e * D0 + k0n + 4 * g];
                if (tid < 128) {
                    int r = tid >> 2, g = tid & 3;
                    av = *(const float4*)&input[(row0 + r) * D0 + k0n + 4 * g];
                }
            }
            // compute tile t from LDS
            #pragma unroll
            for (int kkg = 0; kkg < 4; ++kkg) {
                float4 a[8];
                #pragma unroll
                for (int i = 0; i < 8; ++i)
                    a[i] = *(float4*)&sA[(rg + i) * PA + 4 * kkg];   // broadcast
                #pragma unroll
                for (int p = 0; p < 4; ++p) {
                    float4 b = *(float4*)&sBt[(4 * kkg + p) * PE + cb]; // contiguous
                    #pragma unroll
                    for (int i = 0; i < 8; ++i) {
                        float ai = (p == 0) ? a[i].x : (p == 1) ? a[i].y
                                 : (p == 2) ? a[i].z : a[i].w;
                        acc[i][0] = fmaf(ai, b.x, acc[i][0]);
                        acc[i][1] = fmaf(ai, b.y, acc[i][1]);
                        acc[i][2] = fmaf(ai, b.z, acc[i][2]);
                        acc[i][3] = fmaf(ai, b.w, acc[i][3]);
                    }
                }
            }
            __syncthreads();          // all waves done reading tile t
            if (more) {
                #pragma unroll
                for (int g = 0; g < 4; ++g) {
                    sBt[(4 * g + 0) * PE + e] = w[g].x;
                    sBt[(4 * g + 1) * PE + e] = w[g].y;
                    sBt[(4 * g + 2) * PE + e] = w[g].z;
                    sBt[(4 * g + 3) * PE + e] = w[g].w;
                }
                if (tid < 128) {
                    int r = tid >> 2, g = tid & 3;
                    *(float4*)&sA[r * PA + 4 * g] = av;
                }
                __syncthreads();      // tile t+1 visible
            }
        }
        // write X1 = gelu(acc); no barrier needed before (distinct region,
        // all waves already passed the final compute barrier)
        #pragma unroll
        for (int i = 0; i < 8; ++i) {
            float4 o;
            o.x = gelu_exact(acc[i][0]); o.y = gelu_exact(acc[i][1]);
            o.z = gelu_exact(acc[i][2]); o.w = gelu_exact(acc[i][3]);
            *(float4*)&sX1[(rg + i) * D1 + cb] = o;
        }
    }

    // ================= GEMM2: X2 = gelu(X1 @ W_l1^T), 32x256, K=512 ===========
    {
        const int rg = (wid & 7) * 4;    // 4 rows, wave-uniform
        const int cb = 4 * tcol;         // 4 cols
        const int e  = tid & 255;
        const int h  = tid >> 8;         // 0..1 -> k rows 8h..8h+7

        float acc[4][4];
        #pragma unroll
        for (int i = 0; i < 4; ++i)
            #pragma unroll
            for (int j = 0; j < 4; ++j) acc[i][j] = 0.0f;

        // stage tile 0 (combined with X1 visibility barrier)
        {
            float4 wa = *(const float4*)&W_l1[e * D1 + 8 * h];
            float4 wb = *(const float4*)&W_l1[e * D1 + 8 * h + 4];
            sBt[(8 * h + 0) * PE + e] = wa.x; sBt[(8 * h + 1) * PE + e] = wa.y;
            sBt[(8 * h + 2) * PE + e] = wa.z; sBt[(8 * h + 3) * PE + e] = wa.w;
            sBt[(8 * h + 4) * PE + e] = wb.x; sBt[(8 * h + 5) * PE + e] = wb.y;
            sBt[(8 * h + 6) * PE + e] = wb.z; sBt[(8 * h + 7) * PE + e] = wb.w;
        }
        __syncthreads();

        for (int t = 0; t < D1 / BK; ++t) {
            float4 wa, wb;
            const bool more = (t + 1) < (D1 / BK);
            if (more) {
                const int k0n = (t + 1) * BK;
                wa = *(const float4*)&W_l1[e * D1 + k0n + 8 * h];
                wb = *(const float4*)&W_l1[e * D1 + k0n + 8 * h + 4];
            }
            const int k0 = t * BK;
            #pragma unroll
            for (int kkg = 0; kkg < 4; ++kkg) {
                float4 a[4];
                #pragma unroll
                for (int i = 0; i < 4; ++i)
                    a[i] = *(float4*)&sX1[(rg + i) * D1 + k0 + 4 * kkg]; // broadcast
                #pragma unroll
                for (int p = 0; p < 4; ++p) {
                    float4 b = *(float4*)&sBt[(4 * kkg + p) * PE + cb];
                    #pragma unroll
                    for (int i = 0; i < 4; ++i) {
                        float ai = (p == 0) ? a[i].x : (p == 1) ? a[i].y
                                 : (p == 2) ? a[i].z : a[i].w;
                        acc[i][0] = fmaf(ai, b.x, acc[i][0]);
                        acc[i][1] = fmaf(ai, b.y, acc[i][1]);
                        acc[i][2] = fmaf(ai, b.z, acc[i][2]);
                        acc[i][3] = fmaf(ai, b.w, acc[i][3]);
                    }
                }
            }
            __syncthreads();
            if (more) {
                sBt[(8 * h + 0) * PE + e] = wa.x; sBt[(8 * h + 1) * PE + e] = wa.y;
                sBt[(8 * h + 2) * PE + e] = wa.z; sBt[(8 * h + 3) * PE + e] = wa.w;
                sBt[(8 * h + 4) * PE + e] = wb.x; sBt[(8 * h + 5) * PE + e] = wb.y;
                sBt[(8 * h + 6) * PE + e] = wb.z; sBt[(8 * h + 7) * PE + e] = wb.w;
                __syncthreads();
            }
        }
        #pragma unroll
        for (int i = 0; i < 4; ++i) {
            float4 o;
            o.x = gelu_exact(acc[i][0]); o.y = gelu_exact(acc[i][1]);
            o.z = gelu_exact(acc[i][2]); o.w = gelu_exact(acc[i][3]);
            *(float4*)&sX2[(rg + i) * D2 + cb] = o;
        }
    }

    // ================= GEMM3: X3 = gelu(X2 @ W_l2^T), 32x128, K=256 ===========
    {
        const int rb = wid * 4 + ((tcol >> 5) << 1);  // 2 rows (half-wave-uniform)
        const int cb = 4 * (tcol & 31);               // 4 cols
        const int e  = tid & 127;
        const int g  = tid >> 7;                      // 0..3 -> k rows 4g..4g+3

        float acc[2][4];
        #pragma unroll
        for (int i = 0; i < 2; ++i)
            #pragma unroll
            for (int j = 0; j < 4; ++j) acc[i][j] = 0.0f;

        {
            float4 w = *(const float4*)&W_l2[e * D2 + 4 * g];
            sBt[(4 * g + 0) * PE + e] = w.x; sBt[(4 * g + 1) * PE + e] = w.y;
            sBt[(4 * g + 2) * PE + e] = w.z; sBt[(4 * g + 3) * PE + e] = w.w;
        }
        __syncthreads();

        for (int t = 0; t < D2 / BK; ++t) {
            float4 w;
            const bool more = (t + 1) < (D2 / BK);
            if (more) {
                const int k0n = (t + 1) * BK;
                w = *(const float4*)&W_l2[e * D2 + k0n + 4 * g];
            }
            const int k0 = t * BK;
            #pragma unroll
            for (int kkg = 0; kkg < 4; ++kkg) {
                float4 a[2];
                #pragma unroll
                for (int i = 0; i < 2; ++i)
                    a[i] = *(float4*)&sX2[(rb + i) * D2 + k0 + 4 * kkg];
                #pragma unroll
                for (int p = 0; p < 4; ++p) {
                    float4 b = *(float4*)&sBt[(4 * kkg + p) * PE + cb];
                    #pragma unroll
                    for (int i = 0; i < 2; ++i) {
                        float ai = (p == 0) ? a[i].x : (p == 1) ? a[i].y
                                 : (p == 2) ? a[i].z : a[i].w;
                        acc[i][0] = fmaf(ai, b.x, acc[i][0]);
                        acc[i][1] = fmaf(ai, b.y, acc[i][1]);
                        acc[i][2] = fmaf(ai, b.z, acc[i][2]);
                        acc[i][3] = fmaf(ai, b.w, acc[i][3]);
                    }
                }
            }
            __syncthreads();
            if (more) {
                sBt[(4 * g + 0) * PE + e] = w.x; sBt[(4 * g + 1) * PE + e] = w.y;
                sBt[(4 * g + 2) * PE + e] = w.z; sBt[(4 * g + 3) * PE + e] = w.w;
                __syncthreads();
            }
        }
        #pragma unroll
        for (int i = 0; i < 2; ++i) {
            float4 o;
            o.x = gelu_exact(acc[i][0]); o.y = gelu_exact(acc[i][1]);
            o.z = gelu_exact(acc[i][2]); o.w = gelu_exact(acc[i][3]);
            *(float4*)&sX3[(rb + i) * PX3 + cb] = o;
        }
    }
    __syncthreads();

    // ===== layer4: prob = sigmoid(X3 @ w3); threshold; per-row scale ==========
    {
        const int row = tid >> 4;        // 32 rows x 16 lanes
        const int j   = tid & 15;
        float p = 0.0f;
        #pragma unroll
        for (int t = 0; t < 8; ++t)
            p = fmaf(sX3[row * PX3 + j + 16 * t], W_l3[j + 16 * t], p);
        #pragma unroll
        for (int off = 8; off > 0; off >>= 1)
            p += __shfl_down(p, off, 16);
        if (j == 0) {
            float prob = 1.0f / (1.0f + expf(-p));
            float cm_pre = prob * prev_m[row0 + row];
            float st = (cm_pre > 0.5f) ? 1.0f : 0.0f;
            float cm = st + 1e-10f;
            sM[row] = cm;
            mask_out[row0 + row]  = st;
            currm_out[row0 + row] = cm;
        }
    }
    __syncthreads();

    // ================= epilogue: out = input * curr_m =========================
    #pragma unroll
    for (int it = 0; it < 8; ++it) {
        int j = tid + NT * it;           // < 4096 float4 = 32 rows x 128
        int r = j >> 7;
        int q = (j & 127) << 2;
        float m = sM[r];
        float4 v = *(const float4*)&input[(row0 + r) * D0 + q];
        float4 o;
        o.x = v.x * m; o.y = v.y * m; o.z = v.z * m; o.w = v.w * m;
        *(float4*)&out[(row0 + r) * D0 + q] = o;
    }
}

}  // namespace

extern "C" void kernel_launch(void* const* d_in, const int* in_sizes, int n_in,
                              void* d_out, int out_size, void* d_ws, size_t ws_size,
                              hipStream_t stream) {
    const float* input  = (const float*)d_in[0];
    // d_in[1] = attention_mask: unused by the reference computation
    const float* prev_m = (const float*)d_in[2];
    const float* W_L    = (const float*)d_in[3];
    const float* W_l1   = (const float*)d_in[4];
    const float* W_l2   = (const float*)d_in[5];
    const float* W_l3   = (const float*)d_in[6];

    float* out_p   = (float*)d_out;                  // [R, 512]
    float* mask_p  = out_p + (size_t)R_ROWS * D0;    // [R]
    float* currm_p = mask_p + R_ROWS;                // [R]

    dim3 grid(R_ROWS / TM), block(NT);
    fused_mlp_mask<<<grid, block, 0, stream>>>(input, prev_m, W_L, W_l1, W_l2, W_l3,
                                               out_p, mask_p, currm_p);
}